// Round 2
// baseline (1747.156 us; speedup 1.0000x reference)
//
#include <hip/hip_runtime.h>

typedef __attribute__((ext_vector_type(8))) short bf16x8;
typedef __attribute__((ext_vector_type(4))) float f32x4;

#define NN 50000
#define HH 128

static __device__ __forceinline__ unsigned short f2bf(float f) {
  unsigned u = __builtin_bit_cast(unsigned, f);
  u = u + 0x7FFFu + ((u >> 16) & 1u);
  return (unsigned short)(u >> 16);
}

static __device__ __forceinline__ bf16x8 bfrag(const unsigned short* __restrict__ w,
                                               int kt, int nt, int lane) {
  return *reinterpret_cast<const bf16x8*>(w + (((kt * 8 + nt) * 64 + lane) << 3));
}

// Convert fp32 row-major W[K][128] into bf16 MFMA B-fragment layout:
// out[((kt*8+nt)*64+lane)*8+j] = bf16(W[kt*32+(lane>>4)*8+j][nt*16+(lane&15)])
__global__ void swz_kernel(const float* __restrict__ W, unsigned short* __restrict__ out,
                           int total) {
  int o = blockIdx.x * 256 + threadIdx.x;
  if (o >= total) return;
  int j = o & 7, lane = (o >> 3) & 63, nt = (o >> 9) & 7, kt = o >> 12;
  int row = kt * 32 + (lane >> 4) * 8 + j;
  int col = nt * 16 + (lane & 15);
  out[o] = f2bf(W[row * 128 + col]);
}

// ---- counting-sort by destination ----
__global__ void hist_kernel(const int* __restrict__ ei, int E, int* __restrict__ cnt) {
  int e = blockIdx.x * 256 + threadIdx.x;
  if (e < E) atomicAdd(cnt + ei[E + e], 1);
}

// single-block exclusive scan of n counters (n ~ 50K): 256 threads, chunked
__global__ void scan_kernel(const int* __restrict__ cnt, int* __restrict__ offs, int n) {
  __shared__ int wsum[4];
  __shared__ int running;
  const int t = threadIdx.x, lane = t & 63, w = t >> 6;
  if (t == 0) running = 0;
  __syncthreads();
  for (int base = 0; base < n; base += 256) {
    int i = base + t;
    int v = (i < n) ? cnt[i] : 0;
    int inc = v;
#pragma unroll
    for (int d = 1; d < 64; d <<= 1) {
      int o = __shfl_up(inc, d, 64);
      if (lane >= d) inc += o;
    }
    if (lane == 63) wsum[w] = inc;
    __syncthreads();
    int wo = 0;
    for (int k = 0; k < w; ++k) wo += wsum[k];
    if (i < n) offs[i] = running + wo + inc - v;
    __syncthreads();
    if (t == 255) running += wsum[0] + wsum[1] + wsum[2] + wsum[3];
    __syncthreads();
  }
}

// offs is consumed (post-increment): after this, offs[d] = end offset of segment d
__global__ void scatter_kernel(const int* __restrict__ ei, int E, int* __restrict__ offs,
                               int* __restrict__ perm) {
  int e = blockIdx.x * 256 + threadIdx.x;
  if (e < E) {
    int p = atomicAdd(offs + ei[E + e], 1);
    perm[p] = e;
  }
}

// Per-scale edge message MLP + scatter-add, edges visited in dst-sorted order.
// msg = relu([x[src],x[dst],ea] @ W1 + b1) @ W2 + b2 ; agg[dst] += msg
// K=259 split: x[src]@W1[0:128] + x[dst]@W1[128:256] (MFMA) + ea@W1[256:259] (VALU).
__global__ __launch_bounds__(256) void edge_kernel(
    const float* __restrict__ x, const int* __restrict__ ei, const float* __restrict__ ea,
    const int* __restrict__ perm,
    const float* __restrict__ W1f, const float* __restrict__ b1, const float* __restrict__ b2,
    const unsigned short* __restrict__ W1a, const unsigned short* __restrict__ W1b,
    const unsigned short* __restrict__ W2, float* __restrict__ agg, int E) {
  __shared__ unsigned short As[64][136];   // x[src] bf16, later reused for h1
  __shared__ unsigned short Ad[64][136];   // x[dst] bf16
  __shared__ float eas[64][4];
  __shared__ int dsts[64];
  __shared__ int srcs[64];
  const int t = threadIdx.x;

  // XCD-chunked bijective swizzle (m204): consecutive tiles -> same XCD L2,
  // so dst-sorted tiles keep agg lines hot in one L2.
  const int nwg = gridDim.x, bid = blockIdx.x;
  const int q = nwg >> 3, r = nwg & 7;
  const int xcd = bid & 7, idx = bid >> 3;
  const int swz = (xcd < r ? xcd * (q + 1) : r * (q + 1) + (xcd - r) * q) + idx;
  const int e0 = swz * 64;

  if (t < 64) {
    int ge = e0 + t;
    int oe = (ge < E) ? perm[ge] : -1;
    int s = -1, d = -1;
    float a0 = 0.f, a1 = 0.f, a2 = 0.f;
    if (oe >= 0) {
      s = ei[oe];
      d = ei[E + oe];
      a0 = ea[(long)oe * 3 + 0];
      a1 = ea[(long)oe * 3 + 1];
      a2 = ea[(long)oe * 3 + 2];
    }
    srcs[t] = s; dsts[t] = d;
    eas[t][0] = a0; eas[t][1] = a1; eas[t][2] = a2;
  }
  __syncthreads();

  // Stage: gather + convert 64 edge rows (float4 loads, ushort4 LDS stores)
  for (int idx2 = t; idx2 < 64 * 32; idx2 += 256) {
    int e = idx2 >> 5, c4 = (idx2 & 31) << 2;
    int s = srcs[e], d = dsts[e];
    float4 vs = make_float4(0.f, 0.f, 0.f, 0.f);
    float4 vd = vs;
    if (s >= 0) {
      vs = *reinterpret_cast<const float4*>(x + (long)s * HH + c4);
      vd = *reinterpret_cast<const float4*>(x + (long)d * HH + c4);
    }
    ushort4 us = make_ushort4(f2bf(vs.x), f2bf(vs.y), f2bf(vs.z), f2bf(vs.w));
    ushort4 ud = make_ushort4(f2bf(vd.x), f2bf(vd.y), f2bf(vd.z), f2bf(vd.w));
    *reinterpret_cast<ushort4*>(&As[e][c4]) = us;
    *reinterpret_cast<ushort4*>(&Ad[e][c4]) = ud;
  }
  __syncthreads();

  const int wave = t >> 6, lane = t & 63;
  const int lr = lane & 15, lgp = lane >> 4;

  // GEMM1: h = x_src @ W1a + x_dst @ W1b   (each wave owns 16 edge rows)
  f32x4 acc[8];
#pragma unroll
  for (int nt = 0; nt < 8; ++nt) acc[nt] = (f32x4){0.f, 0.f, 0.f, 0.f};
#pragma unroll
  for (int kt = 0; kt < 4; ++kt) {
    bf16x8 a_s = *reinterpret_cast<const bf16x8*>(&As[wave * 16 + lr][kt * 32 + lgp * 8]);
    bf16x8 a_d = *reinterpret_cast<const bf16x8*>(&Ad[wave * 16 + lr][kt * 32 + lgp * 8]);
#pragma unroll
    for (int nt = 0; nt < 8; ++nt) {
      acc[nt] = __builtin_amdgcn_mfma_f32_16x16x32_bf16(a_s, bfrag(W1a, kt, nt, lane), acc[nt], 0, 0, 0);
      acc[nt] = __builtin_amdgcn_mfma_f32_16x16x32_bf16(a_d, bfrag(W1b, kt, nt, lane), acc[nt], 0, 0, 0);
    }
  }

  // Epilogue 1: + b1 + ea rank-3 (fp32), relu, h1 -> LDS (wave-private rows, no barrier)
  // C layout: row = wave*16 + lgp*4 + r, col = nt*16 + lr
#pragma unroll
  for (int nt = 0; nt < 8; ++nt) {
    int col = nt * 16 + lr;
    float wc0 = W1f[256 * HH + col];
    float wc1 = W1f[257 * HH + col];
    float wc2 = W1f[258 * HH + col];
    float bb = b1[col];
#pragma unroll
    for (int r = 0; r < 4; ++r) {
      int row = wave * 16 + lgp * 4 + r;
      float v = acc[nt][r] + bb + eas[row][0] * wc0 + eas[row][1] * wc1 + eas[row][2] * wc2;
      As[row][col] = f2bf(fmaxf(v, 0.f));
    }
  }

  // GEMM2: msg = h1 @ W2
  f32x4 acc2[8];
#pragma unroll
  for (int nt = 0; nt < 8; ++nt) acc2[nt] = (f32x4){0.f, 0.f, 0.f, 0.f};
#pragma unroll
  for (int kt = 0; kt < 4; ++kt) {
    bf16x8 a = *reinterpret_cast<const bf16x8*>(&As[wave * 16 + lr][kt * 32 + lgp * 8]);
#pragma unroll
    for (int nt = 0; nt < 8; ++nt) {
      acc2[nt] = __builtin_amdgcn_mfma_f32_16x16x32_bf16(a, bfrag(W2, kt, nt, lane), acc2[nt], 0, 0, 0);
    }
  }

  // Scatter: agg[dst] += msg + b2 (dsts sorted -> lines stay hot in this XCD's L2)
#pragma unroll
  for (int nt = 0; nt < 8; ++nt) {
    int col = nt * 16 + lr;
    float bb = b2[col];
#pragma unroll
    for (int r = 0; r < 4; ++r) {
      int row = wave * 16 + lgp * 4 + r;
      int d = dsts[row];
      if (d >= 0) atomicAdd(agg + (long)d * HH + col, acc2[nt][r] + bb);
    }
  }
}

// Node update: u=[x,la,ma,lo]; gate=sigmoid(u@Wg+bg); upd=relu(u@Wu1+bu1)@Wu2+bu2;
// out = LN(gate*upd + (1-gate)*x) * gamma + beta
__global__ __launch_bounds__(256) void node_kernel(
    const float* __restrict__ x, const float* __restrict__ la, const float* __restrict__ ma,
    const float* __restrict__ lo,
    const unsigned short* __restrict__ Wg, const unsigned short* __restrict__ Wu1,
    const unsigned short* __restrict__ Wu2,
    const float* __restrict__ bg, const float* __restrict__ bu1, const float* __restrict__ bu2,
    const float* __restrict__ gamma, const float* __restrict__ beta,
    float* __restrict__ out) {
  __shared__ unsigned short Hs[64][136];
  const int t = threadIdx.x;
  const int n0 = blockIdx.x * 64;
  const int wave = t >> 6, lane = t & 63;
  const int lr = lane & 15, lgp = lane >> 4;

  f32x4 accG[8], accH[8];
#pragma unroll
  for (int nt = 0; nt < 8; ++nt) {
    accG[nt] = (f32x4){0.f, 0.f, 0.f, 0.f};
    accH[nt] = (f32x4){0.f, 0.f, 0.f, 0.f};
  }
  const int arow = n0 + wave * 16 + lr;
  const bool aok = arow < NN;

  // K=512 over [x | la | ma | lo], A-fragments straight from global (contiguous rows)
#pragma unroll
  for (int kt = 0; kt < 16; ++kt) {
    const float* S = (kt < 4) ? x : (kt < 8) ? la : (kt < 12) ? ma : lo;
    int cb = ((kt & 3) << 5) + (lgp << 3);
    bf16x8 a;
    if (aok) {
      float4 f0 = *reinterpret_cast<const float4*>(S + (long)arow * HH + cb);
      float4 f1 = *reinterpret_cast<const float4*>(S + (long)arow * HH + cb + 4);
      a[0] = (short)f2bf(f0.x); a[1] = (short)f2bf(f0.y);
      a[2] = (short)f2bf(f0.z); a[3] = (short)f2bf(f0.w);
      a[4] = (short)f2bf(f1.x); a[5] = (short)f2bf(f1.y);
      a[6] = (short)f2bf(f1.z); a[7] = (short)f2bf(f1.w);
    } else {
      a = (bf16x8){0, 0, 0, 0, 0, 0, 0, 0};
    }
#pragma unroll
    for (int nt = 0; nt < 8; ++nt) {
      accG[nt] = __builtin_amdgcn_mfma_f32_16x16x32_bf16(a, bfrag(Wg, kt, nt, lane), accG[nt], 0, 0, 0);
      accH[nt] = __builtin_amdgcn_mfma_f32_16x16x32_bf16(a, bfrag(Wu1, kt, nt, lane), accH[nt], 0, 0, 0);
    }
  }

  // gate = sigmoid(accG+bg) kept in regs; h1 = relu(accH+bu1) -> LDS bf16
#pragma unroll
  for (int nt = 0; nt < 8; ++nt) {
    int col = nt * 16 + lr;
    float bgv = bg[col], bhv = bu1[col];
#pragma unroll
    for (int r = 0; r < 4; ++r) {
      float g = 1.f / (1.f + __expf(-(accG[nt][r] + bgv)));
      accG[nt][r] = g;
      float h = fmaxf(accH[nt][r] + bhv, 0.f);
      Hs[wave * 16 + lgp * 4 + r][col] = f2bf(h);
    }
  }

  // GEMM2: upd = h1 @ Wu2
  f32x4 accU[8];
#pragma unroll
  for (int nt = 0; nt < 8; ++nt) accU[nt] = (f32x4){0.f, 0.f, 0.f, 0.f};
#pragma unroll
  for (int kt = 0; kt < 4; ++kt) {
    bf16x8 a = *reinterpret_cast<const bf16x8*>(&Hs[wave * 16 + lr][kt * 32 + lgp * 8]);
#pragma unroll
    for (int nt = 0; nt < 8; ++nt) {
      accU[nt] = __builtin_amdgcn_mfma_f32_16x16x32_bf16(a, bfrag(Wu2, kt, nt, lane), accU[nt], 0, 0, 0);
    }
  }

  // combine: v = gate*upd + (1-gate)*x   (store v back into accU)
#pragma unroll
  for (int nt = 0; nt < 8; ++nt) {
    int col = nt * 16 + lr;
    float b2v = bu2[col];
#pragma unroll
    for (int r = 0; r < 4; ++r) {
      int row = n0 + wave * 16 + lgp * 4 + r;
      float xv = (row < NN) ? x[(long)row * HH + col] : 0.f;
      float u = accU[nt][r] + b2v;
      float g = accG[nt][r];
      accU[nt][r] = g * u + (1.f - g) * xv;
    }
  }

  // LayerNorm per row (16 lanes share a row-group; reduce via shfl_xor 1,2,4,8)
#pragma unroll
  for (int r = 0; r < 4; ++r) {
    int row = n0 + wave * 16 + lgp * 4 + r;
    float s = 0.f;
#pragma unroll
    for (int nt = 0; nt < 8; ++nt) s += accU[nt][r];
    s += __shfl_xor(s, 1, 64);
    s += __shfl_xor(s, 2, 64);
    s += __shfl_xor(s, 4, 64);
    s += __shfl_xor(s, 8, 64);
    float mu = s * (1.f / 128.f);
    float q = 0.f;
#pragma unroll
    for (int nt = 0; nt < 8; ++nt) {
      float d = accU[nt][r] - mu;
      q += d * d;
    }
    q += __shfl_xor(q, 1, 64);
    q += __shfl_xor(q, 2, 64);
    q += __shfl_xor(q, 4, 64);
    q += __shfl_xor(q, 8, 64);
    float rs = rsqrtf(q * (1.f / 128.f) + 1e-5f);
    if (row < NN) {
#pragma unroll
      for (int nt = 0; nt < 8; ++nt) {
        int col = nt * 16 + lr;
        out[(long)row * HH + col] = (accU[nt][r] - mu) * rs * gamma[col] + beta[col];
      }
    }
  }
}

extern "C" void kernel_launch(void* const* d_in, const int* in_sizes, int n_in,
                              void* d_out, int out_size, void* d_ws, size_t ws_size,
                              hipStream_t stream) {
  const float* x = (const float*)d_in[0];
  const int* ei_l = (const int*)d_in[1];
  const float* ea_l = (const float*)d_in[2];
  const int* ei_m = (const int*)d_in[3];
  const float* ea_m = (const float*)d_in[4];
  const int* ei_g = (const int*)d_in[5];
  const float* ea_g = (const float*)d_in[6];
  const float* Wa1 = (const float*)d_in[7];
  const float* ba1 = (const float*)d_in[8];
  const float* Wa2 = (const float*)d_in[9];
  const float* ba2 = (const float*)d_in[10];
  const float* Wb1 = (const float*)d_in[11];
  const float* bb1 = (const float*)d_in[12];
  const float* Wb2 = (const float*)d_in[13];
  const float* bb2 = (const float*)d_in[14];
  const float* Wc1 = (const float*)d_in[15];
  const float* bc1 = (const float*)d_in[16];
  const float* Wc2 = (const float*)d_in[17];
  const float* bc2 = (const float*)d_in[18];
  const float* Wg = (const float*)d_in[19];
  const float* bg = (const float*)d_in[20];
  const float* Wu1 = (const float*)d_in[21];
  const float* bu1 = (const float*)d_in[22];
  const float* Wu2 = (const float*)d_in[23];
  const float* bu2 = (const float*)d_in[24];
  const float* gamma = (const float*)d_in[25];
  const float* beta = (const float*)d_in[26];

  const int El = in_sizes[1] / 2;
  const int Em = in_sizes[3] / 2;
  const int Eg = in_sizes[5] / 2;

  // Workspace layout
  float* la = (float*)d_ws;                 // N*H
  float* ma = la + (size_t)NN * HH;         // N*H
  float* lo = ma + (size_t)NN * HH;         // N*H
  unsigned short* wp = (unsigned short*)(lo + (size_t)NN * HH);
  unsigned short* W1a_a = wp; wp += 128 * 128;
  unsigned short* W1b_a = wp; wp += 128 * 128;
  unsigned short* W2_a  = wp; wp += 128 * 128;
  unsigned short* W1a_b = wp; wp += 128 * 128;
  unsigned short* W1b_b = wp; wp += 128 * 128;
  unsigned short* W2_b  = wp; wp += 128 * 128;
  unsigned short* W1a_c = wp; wp += 128 * 128;
  unsigned short* W1b_c = wp; wp += 128 * 128;
  unsigned short* W2_c  = wp; wp += 128 * 128;
  unsigned short* Wg_s  = wp; wp += 512 * 128;
  unsigned short* Wu1_s = wp; wp += 512 * 128;
  unsigned short* Wu2_s = wp; wp += 128 * 128;
  int* ip = (int*)wp;
  int* perm_l = ip; ip += El;
  int* perm_m = ip; ip += Em;
  int* perm_g = ip; ip += Eg;
  int* cnt  = ip; ip += NN;
  int* offs = ip; ip += NN;

  // Zero the three aggregation buffers
  hipMemsetAsync(d_ws, 0, (size_t)3 * NN * HH * sizeof(float), stream);

  // Weight swizzle pre-passes (bf16 B-fragment layout)
  auto swz = [&](const float* W, unsigned short* o, int K) {
    int total = K * 128;
    swz_kernel<<<(total + 255) / 256, 256, 0, stream>>>(W, o, total);
  };
  swz(Wa1, W1a_a, 128); swz(Wa1 + 128 * 128, W1b_a, 128); swz(Wa2, W2_a, 128);
  swz(Wb1, W1a_b, 128); swz(Wb1 + 128 * 128, W1b_b, 128); swz(Wb2, W2_b, 128);
  swz(Wc1, W1a_c, 128); swz(Wc1 + 128 * 128, W1b_c, 128); swz(Wc2, W2_c, 128);
  swz(Wg, Wg_s, 512);   swz(Wu1, Wu1_s, 512);             swz(Wu2, Wu2_s, 128);

  // Counting sort by dst for each scale (hist -> scan -> scatter)
  auto sort_scale = [&](const int* ei, int E, int* perm) {
    hipMemsetAsync(cnt, 0, NN * sizeof(int), stream);
    hist_kernel<<<(E + 255) / 256, 256, 0, stream>>>(ei, E, cnt);
    scan_kernel<<<1, 256, 0, stream>>>(cnt, offs, NN);
    scatter_kernel<<<(E + 255) / 256, 256, 0, stream>>>(ei, E, offs, perm);
  };
  sort_scale(ei_l, El, perm_l);
  sort_scale(ei_m, Em, perm_m);
  sort_scale(ei_g, Eg, perm_g);

  // Edge message passes (dst-sorted order)
  edge_kernel<<<(El + 63) / 64, 256, 0, stream>>>(x, ei_l, ea_l, perm_l, Wa1, ba1, ba2,
                                                  W1a_a, W1b_a, W2_a, la, El);
  edge_kernel<<<(Em + 63) / 64, 256, 0, stream>>>(x, ei_m, ea_m, perm_m, Wb1, bb1, bb2,
                                                  W1a_b, W1b_b, W2_b, ma, Em);
  edge_kernel<<<(Eg + 63) / 64, 256, 0, stream>>>(x, ei_g, ea_g, perm_g, Wc1, bc1, bc2,
                                                  W1a_c, W1b_c, W2_c, lo, Eg);

  // Node update + LayerNorm
  node_kernel<<<(NN + 63) / 64, 256, 0, stream>>>(x, la, ma, lo, Wg_s, Wu1_s, Wu2_s,
                                                  bg, bu1, bu2, gamma, beta, (float*)d_out);
}

// Round 3
// 596.474 us; speedup vs baseline: 2.9291x; 2.9291x over previous
//
#include <hip/hip_runtime.h>

typedef __attribute__((ext_vector_type(8))) short bf16x8;
typedef __attribute__((ext_vector_type(4))) float f32x4;

#define NN 50000
#define HH 128

static __device__ __forceinline__ unsigned short f2bf(float f) {
  unsigned u = __builtin_bit_cast(unsigned, f);
  u = u + 0x7FFFu + ((u >> 16) & 1u);
  return (unsigned short)(u >> 16);
}

static __device__ __forceinline__ bf16x8 bfrag(const unsigned short* __restrict__ w,
                                               int kt, int nt, int lane) {
  return *reinterpret_cast<const bf16x8*>(w + (((kt * 8 + nt) * 64 + lane) << 3));
}

// Convert fp32 row-major W[K][128] into bf16 MFMA B-fragment layout.
__global__ void swz_kernel(const float* __restrict__ W, unsigned short* __restrict__ out,
                           int total) {
  int o = blockIdx.x * 256 + threadIdx.x;
  if (o >= total) return;
  int j = o & 7, lane = (o >> 3) & 63, nt = (o >> 9) & 7, kt = o >> 12;
  int row = kt * 32 + (lane >> 4) * 8 + j;
  int col = nt * 16 + (lane & 15);
  out[o] = f2bf(W[row * 128 + col]);
}

// ---- counting-sort by destination (two-level parallel scan) ----
__global__ void hist_kernel(const int* __restrict__ ei, int E, int* __restrict__ cnt) {
  int e = blockIdx.x * 256 + threadIdx.x;
  if (e < E) atomicAdd(cnt + ei[E + e], 1);
}

// per-block exclusive scan of 1024-chunks + block sums
__global__ void scanA_kernel(const int* __restrict__ cnt, int* __restrict__ offs,
                             int* __restrict__ bsum, int n) {
  const int t = threadIdx.x, lane = t & 63, w = t >> 6;
  const int i = blockIdx.x * 1024 + t;
  __shared__ int wsum[16], wpre[16];
  int v = (i < n) ? cnt[i] : 0;
  int inc = v;
#pragma unroll
  for (int d = 1; d < 64; d <<= 1) {
    int o = __shfl_up(inc, d, 64);
    if (lane >= d) inc += o;
  }
  if (lane == 63) wsum[w] = inc;
  __syncthreads();
  if (t == 0) {
    int run = 0;
#pragma unroll
    for (int k = 0; k < 16; ++k) { wpre[k] = run; run += wsum[k]; }
    wsum[0] = run;
  }
  __syncthreads();
  if (i < n) offs[i] = wpre[w] + inc - v;
  if (t == 0) bsum[blockIdx.x] = wsum[0];
}

// exclusive scan of block sums (n <= 256), in place
__global__ void scanB_kernel(int* __restrict__ bsum, int n) {
  const int t = threadIdx.x, lane = t & 63, w = t >> 6;
  __shared__ int wsum[4];
  int v = (t < n) ? bsum[t] : 0;
  int inc = v;
#pragma unroll
  for (int d = 1; d < 64; d <<= 1) {
    int o = __shfl_up(inc, d, 64);
    if (lane >= d) inc += o;
  }
  if (lane == 63) wsum[w] = inc;
  __syncthreads();
  int wo = 0;
  for (int k = 0; k < w; ++k) wo += wsum[k];
  if (t < n) bsum[t] = wo + inc - v;
}

__global__ void scanC_kernel(int* __restrict__ offs, const int* __restrict__ bsum, int n) {
  int i = blockIdx.x * 1024 + threadIdx.x;
  if (i < n) offs[i] += bsum[blockIdx.x];
}

// offs region is consumed (post-increment). perm gets ORIGINAL edge ids in dst-sorted order.
__global__ void scatter_kernel(const int* __restrict__ ei, int E, int* __restrict__ offs,
                               int base, int* __restrict__ perm) {
  int e = blockIdx.x * 256 + threadIdx.x;
  if (e < E) {
    int p = atomicAdd(offs + ei[E + e], 1);
    perm[p - base] = e;
  }
}

// Per-scale edge message MLP + segment-reduced scatter-add (edges dst-sorted via perm).
// msg = relu([x[src],x[dst],ea] @ W1 + b1) @ W2 + b2 ; agg[dst] += msg
__global__ __launch_bounds__(256) void edge_kernel(
    const float* __restrict__ x, const int* __restrict__ ei, const float* __restrict__ ea,
    const int* __restrict__ perm,
    const float* __restrict__ W1f, const float* __restrict__ b1, const float* __restrict__ b2,
    const unsigned short* __restrict__ W1a, const unsigned short* __restrict__ W1b,
    const unsigned short* __restrict__ W2, float* __restrict__ agg, int E) {
  // union: As[64][136] bf16 | Ad[64][136] bf16  (34816 B)  --later--> msgf[64][128] f32 (32768 B)
  __shared__ char smem[64 * 136 * 2 * 2];
  unsigned short (*As)[136] = (unsigned short(*)[136])smem;
  unsigned short (*Ad)[136] = (unsigned short(*)[136])(smem + 64 * 136 * 2);
  float* msgf = (float*)smem;
  __shared__ float eas[64][4];
  __shared__ int dsts[64];
  __shared__ int srcs[64];
  __shared__ int heads[64];
  __shared__ int nheads_s;
  const int t = threadIdx.x;

  // XCD-chunked bijective swizzle (m204): consecutive sorted tiles -> same XCD.
  const int nwg = gridDim.x, bid = blockIdx.x;
  const int q = nwg >> 3, r = nwg & 7;
  const int xcd = bid & 7, idx = bid >> 3;
  const int swz = (xcd < r ? xcd * (q + 1) : r * (q + 1) + (xcd - r) * q) + idx;
  const int e0 = swz * 64;

  if (t < 64) {
    int ge = e0 + t;
    int oe = (ge < E) ? perm[ge] : -1;
    int s = -1, d = -1;
    float a0 = 0.f, a1 = 0.f, a2 = 0.f;
    if (oe >= 0) {
      s = ei[oe];
      d = ei[E + oe];
      a0 = ea[(long)oe * 3 + 0];
      a1 = ea[(long)oe * 3 + 1];
      a2 = ea[(long)oe * 3 + 2];
    }
    srcs[t] = s; dsts[t] = d;
    eas[t][0] = a0; eas[t][1] = a1; eas[t][2] = a2;
    // segment heads over sorted dsts (wave 0 only)
    bool ishead = (d >= 0) && (t == 0 || dsts[t - 1] != d);
    unsigned long long mask = __ballot(ishead);
    if (ishead) {
      int rank = __popcll(mask & ((1ull << t) - 1ull));
      heads[rank] = t;
    }
    if (t == 0) nheads_s = __popcll(mask);
  }
  __syncthreads();

  // Stage: gather + convert 64 edge rows (float4 loads, ushort4 LDS stores)
  for (int idx2 = t; idx2 < 64 * 32; idx2 += 256) {
    int e = idx2 >> 5, c4 = (idx2 & 31) << 2;
    int s = srcs[e], d = dsts[e];
    float4 vs = make_float4(0.f, 0.f, 0.f, 0.f);
    float4 vd = vs;
    if (s >= 0) {
      vs = *reinterpret_cast<const float4*>(x + (long)s * HH + c4);
      vd = *reinterpret_cast<const float4*>(x + (long)d * HH + c4);
    }
    ushort4 us = make_ushort4(f2bf(vs.x), f2bf(vs.y), f2bf(vs.z), f2bf(vs.w));
    ushort4 ud = make_ushort4(f2bf(vd.x), f2bf(vd.y), f2bf(vd.z), f2bf(vd.w));
    *reinterpret_cast<ushort4*>(&As[e][c4]) = us;
    *reinterpret_cast<ushort4*>(&Ad[e][c4]) = ud;
  }
  __syncthreads();

  const int wave = t >> 6, lane = t & 63;
  const int lr = lane & 15, lgp = lane >> 4;

  // GEMM1: h = x_src @ W1a + x_dst @ W1b   (each wave owns 16 edge rows)
  f32x4 acc[8];
#pragma unroll
  for (int nt = 0; nt < 8; ++nt) acc[nt] = (f32x4){0.f, 0.f, 0.f, 0.f};
#pragma unroll
  for (int kt = 0; kt < 4; ++kt) {
    bf16x8 a_s = *reinterpret_cast<const bf16x8*>(&As[wave * 16 + lr][kt * 32 + lgp * 8]);
    bf16x8 a_d = *reinterpret_cast<const bf16x8*>(&Ad[wave * 16 + lr][kt * 32 + lgp * 8]);
#pragma unroll
    for (int nt = 0; nt < 8; ++nt) {
      acc[nt] = __builtin_amdgcn_mfma_f32_16x16x32_bf16(a_s, bfrag(W1a, kt, nt, lane), acc[nt], 0, 0, 0);
      acc[nt] = __builtin_amdgcn_mfma_f32_16x16x32_bf16(a_d, bfrag(W1b, kt, nt, lane), acc[nt], 0, 0, 0);
    }
  }

  // Epilogue 1: + b1 + ea rank-3 (fp32), relu, h1 -> LDS (wave-private rows, no barrier)
#pragma unroll
  for (int nt = 0; nt < 8; ++nt) {
    int col = nt * 16 + lr;
    float wc0 = W1f[256 * HH + col];
    float wc1 = W1f[257 * HH + col];
    float wc2 = W1f[258 * HH + col];
    float bb = b1[col];
#pragma unroll
    for (int r = 0; r < 4; ++r) {
      int row = wave * 16 + lgp * 4 + r;
      float v = acc[nt][r] + bb + eas[row][0] * wc0 + eas[row][1] * wc1 + eas[row][2] * wc2;
      As[row][col] = f2bf(fmaxf(v, 0.f));
    }
  }

  // GEMM2: msg = h1 @ W2 (reads own wave's As rows only)
  f32x4 acc2[8];
#pragma unroll
  for (int nt = 0; nt < 8; ++nt) acc2[nt] = (f32x4){0.f, 0.f, 0.f, 0.f};
#pragma unroll
  for (int kt = 0; kt < 4; ++kt) {
    bf16x8 a = *reinterpret_cast<const bf16x8*>(&As[wave * 16 + lr][kt * 32 + lgp * 8]);
#pragma unroll
    for (int nt = 0; nt < 8; ++nt) {
      acc2[nt] = __builtin_amdgcn_mfma_f32_16x16x32_bf16(a, bfrag(W2, kt, nt, lane), acc2[nt], 0, 0, 0);
    }
  }

  __syncthreads();  // everyone done reading As/Ad -> safe to overlay msgf

  // msg rows (+b2) -> LDS fp32; invalid rows -> 0
#pragma unroll
  for (int nt = 0; nt < 8; ++nt) {
    int col = nt * 16 + lr;
    float bb = b2[col];
#pragma unroll
    for (int r = 0; r < 4; ++r) {
      int row = wave * 16 + lgp * 4 + r;
      msgf[row * 128 + col] = (dsts[row] >= 0) ? acc2[nt][r] + bb : 0.f;
    }
  }
  __syncthreads();

  // Segment reduce in LDS, one atomicAdd per (unique dst, col)
  const int nh = nheads_s;
  const int col = t & 127;
  for (int hi = t >> 7; hi < nh; hi += 2) {
    int h = heads[hi];
    int en = (hi + 1 < nh) ? heads[hi + 1] : 64;
    float s = 0.f;
    for (int rr = h; rr < en; ++rr) s += msgf[rr * 128 + col];
    atomicAdd(agg + (long)dsts[h] * HH + col, s);
  }
}

// Node update: u=[x,la,ma,lo]; gate=sigmoid(u@Wg+bg); upd=relu(u@Wu1+bu1)@Wu2+bu2;
// out = LN(gate*upd + (1-gate)*x) * gamma + beta
__global__ __launch_bounds__(256) void node_kernel(
    const float* __restrict__ x, const float* __restrict__ la, const float* __restrict__ ma,
    const float* __restrict__ lo,
    const unsigned short* __restrict__ Wg, const unsigned short* __restrict__ Wu1,
    const unsigned short* __restrict__ Wu2,
    const float* __restrict__ bg, const float* __restrict__ bu1, const float* __restrict__ bu2,
    const float* __restrict__ gamma, const float* __restrict__ beta,
    float* __restrict__ out) {
  __shared__ unsigned short Hs[64][136];
  const int t = threadIdx.x;
  const int n0 = blockIdx.x * 64;
  const int wave = t >> 6, lane = t & 63;
  const int lr = lane & 15, lgp = lane >> 4;

  f32x4 accG[8], accH[8];
#pragma unroll
  for (int nt = 0; nt < 8; ++nt) {
    accG[nt] = (f32x4){0.f, 0.f, 0.f, 0.f};
    accH[nt] = (f32x4){0.f, 0.f, 0.f, 0.f};
  }
  const int arow = n0 + wave * 16 + lr;
  const bool aok = arow < NN;

#pragma unroll
  for (int kt = 0; kt < 16; ++kt) {
    const float* S = (kt < 4) ? x : (kt < 8) ? la : (kt < 12) ? ma : lo;
    int cb = ((kt & 3) << 5) + (lgp << 3);
    bf16x8 a;
    if (aok) {
      float4 f0 = *reinterpret_cast<const float4*>(S + (long)arow * HH + cb);
      float4 f1 = *reinterpret_cast<const float4*>(S + (long)arow * HH + cb + 4);
      a[0] = (short)f2bf(f0.x); a[1] = (short)f2bf(f0.y);
      a[2] = (short)f2bf(f0.z); a[3] = (short)f2bf(f0.w);
      a[4] = (short)f2bf(f1.x); a[5] = (short)f2bf(f1.y);
      a[6] = (short)f2bf(f1.z); a[7] = (short)f2bf(f1.w);
    } else {
      a = (bf16x8){0, 0, 0, 0, 0, 0, 0, 0};
    }
#pragma unroll
    for (int nt = 0; nt < 8; ++nt) {
      accG[nt] = __builtin_amdgcn_mfma_f32_16x16x32_bf16(a, bfrag(Wg, kt, nt, lane), accG[nt], 0, 0, 0);
      accH[nt] = __builtin_amdgcn_mfma_f32_16x16x32_bf16(a, bfrag(Wu1, kt, nt, lane), accH[nt], 0, 0, 0);
    }
  }

#pragma unroll
  for (int nt = 0; nt < 8; ++nt) {
    int col = nt * 16 + lr;
    float bgv = bg[col], bhv = bu1[col];
#pragma unroll
    for (int r = 0; r < 4; ++r) {
      float g = 1.f / (1.f + __expf(-(accG[nt][r] + bgv)));
      accG[nt][r] = g;
      float h = fmaxf(accH[nt][r] + bhv, 0.f);
      Hs[wave * 16 + lgp * 4 + r][col] = f2bf(h);
    }
  }

  f32x4 accU[8];
#pragma unroll
  for (int nt = 0; nt < 8; ++nt) accU[nt] = (f32x4){0.f, 0.f, 0.f, 0.f};
#pragma unroll
  for (int kt = 0; kt < 4; ++kt) {
    bf16x8 a = *reinterpret_cast<const bf16x8*>(&Hs[wave * 16 + lr][kt * 32 + lgp * 8]);
#pragma unroll
    for (int nt = 0; nt < 8; ++nt) {
      accU[nt] = __builtin_amdgcn_mfma_f32_16x16x32_bf16(a, bfrag(Wu2, kt, nt, lane), accU[nt], 0, 0, 0);
    }
  }

#pragma unroll
  for (int nt = 0; nt < 8; ++nt) {
    int col = nt * 16 + lr;
    float b2v = bu2[col];
#pragma unroll
    for (int r = 0; r < 4; ++r) {
      int row = n0 + wave * 16 + lgp * 4 + r;
      float xv = (row < NN) ? x[(long)row * HH + col] : 0.f;
      float u = accU[nt][r] + b2v;
      float g = accG[nt][r];
      accU[nt][r] = g * u + (1.f - g) * xv;
    }
  }

#pragma unroll
  for (int r = 0; r < 4; ++r) {
    int row = n0 + wave * 16 + lgp * 4 + r;
    float s = 0.f;
#pragma unroll
    for (int nt = 0; nt < 8; ++nt) s += accU[nt][r];
    s += __shfl_xor(s, 1, 64);
    s += __shfl_xor(s, 2, 64);
    s += __shfl_xor(s, 4, 64);
    s += __shfl_xor(s, 8, 64);
    float mu = s * (1.f / 128.f);
    float q = 0.f;
#pragma unroll
    for (int nt = 0; nt < 8; ++nt) {
      float d = accU[nt][r] - mu;
      q += d * d;
    }
    q += __shfl_xor(q, 1, 64);
    q += __shfl_xor(q, 2, 64);
    q += __shfl_xor(q, 4, 64);
    q += __shfl_xor(q, 8, 64);
    float rs = rsqrtf(q * (1.f / 128.f) + 1e-5f);
    if (row < NN) {
#pragma unroll
      for (int nt = 0; nt < 8; ++nt) {
        int col = nt * 16 + lr;
        out[(long)row * HH + col] = (accU[nt][r] - mu) * rs * gamma[col] + beta[col];
      }
    }
  }
}

extern "C" void kernel_launch(void* const* d_in, const int* in_sizes, int n_in,
                              void* d_out, int out_size, void* d_ws, size_t ws_size,
                              hipStream_t stream) {
  const float* x = (const float*)d_in[0];
  const int* ei_l = (const int*)d_in[1];
  const float* ea_l = (const float*)d_in[2];
  const int* ei_m = (const int*)d_in[3];
  const float* ea_m = (const float*)d_in[4];
  const int* ei_g = (const int*)d_in[5];
  const float* ea_g = (const float*)d_in[6];
  const float* Wa1 = (const float*)d_in[7];
  const float* ba1 = (const float*)d_in[8];
  const float* Wa2 = (const float*)d_in[9];
  const float* ba2 = (const float*)d_in[10];
  const float* Wb1 = (const float*)d_in[11];
  const float* bb1 = (const float*)d_in[12];
  const float* Wb2 = (const float*)d_in[13];
  const float* bb2 = (const float*)d_in[14];
  const float* Wc1 = (const float*)d_in[15];
  const float* bc1 = (const float*)d_in[16];
  const float* Wc2 = (const float*)d_in[17];
  const float* bc2 = (const float*)d_in[18];
  const float* Wg = (const float*)d_in[19];
  const float* bg = (const float*)d_in[20];
  const float* Wu1 = (const float*)d_in[21];
  const float* bu1 = (const float*)d_in[22];
  const float* Wu2 = (const float*)d_in[23];
  const float* bu2 = (const float*)d_in[24];
  const float* gamma = (const float*)d_in[25];
  const float* beta = (const float*)d_in[26];

  const int El = in_sizes[1] / 2;
  const int Em = in_sizes[3] / 2;
  const int Eg = in_sizes[5] / 2;

  // Workspace layout
  float* la = (float*)d_ws;                 // N*H
  float* ma = la + (size_t)NN * HH;         // N*H
  float* lo = ma + (size_t)NN * HH;         // N*H
  unsigned short* wp = (unsigned short*)(lo + (size_t)NN * HH);
  unsigned short* W1a_a = wp; wp += 128 * 128;
  unsigned short* W1b_a = wp; wp += 128 * 128;
  unsigned short* W2_a  = wp; wp += 128 * 128;
  unsigned short* W1a_b = wp; wp += 128 * 128;
  unsigned short* W1b_b = wp; wp += 128 * 128;
  unsigned short* W2_b  = wp; wp += 128 * 128;
  unsigned short* W1a_c = wp; wp += 128 * 128;
  unsigned short* W1b_c = wp; wp += 128 * 128;
  unsigned short* W2_c  = wp; wp += 128 * 128;
  unsigned short* Wg_s  = wp; wp += 512 * 128;
  unsigned short* Wu1_s = wp; wp += 512 * 128;
  unsigned short* Wu2_s = wp; wp += 128 * 128;
  int* ip = (int*)wp;
  int* perm_l = ip; ip += El;
  int* perm_m = ip; ip += Em;
  int* perm_g = ip; ip += Eg;
  int* cnt  = ip; ip += 3 * NN;   // concatenated histograms [l|m|g]
  int* offs = ip; ip += 3 * NN;
  int* bsum = ip; ip += 256;

  // Zero aggregation buffers + histograms
  hipMemsetAsync(d_ws, 0, (size_t)3 * NN * HH * sizeof(float), stream);
  hipMemsetAsync(cnt, 0, 3 * NN * sizeof(int), stream);

  // Weight swizzle pre-passes (bf16 B-fragment layout)
  auto swz = [&](const float* W, unsigned short* o, int K) {
    int total = K * 128;
    swz_kernel<<<(total + 255) / 256, 256, 0, stream>>>(W, o, total);
  };
  swz(Wa1, W1a_a, 128); swz(Wa1 + 128 * 128, W1b_a, 128); swz(Wa2, W2_a, 128);
  swz(Wb1, W1a_b, 128); swz(Wb1 + 128 * 128, W1b_b, 128); swz(Wb2, W2_b, 128);
  swz(Wc1, W1a_c, 128); swz(Wc1 + 128 * 128, W1b_c, 128); swz(Wc2, W2_c, 128);
  swz(Wg, Wg_s, 512);   swz(Wu1, Wu1_s, 512);             swz(Wu2, Wu2_s, 128);

  // Counting sort by dst: concatenated hist -> two-level scan -> scatter
  hist_kernel<<<(El + 255) / 256, 256, 0, stream>>>(ei_l, El, cnt);
  hist_kernel<<<(Em + 255) / 256, 256, 0, stream>>>(ei_m, Em, cnt + NN);
  hist_kernel<<<(Eg + 255) / 256, 256, 0, stream>>>(ei_g, Eg, cnt + 2 * NN);
  const int n3 = 3 * NN;
  const int nblkA = (n3 + 1023) / 1024;
  scanA_kernel<<<nblkA, 1024, 0, stream>>>(cnt, offs, bsum, n3);
  scanB_kernel<<<1, 256, 0, stream>>>(bsum, nblkA);
  scanC_kernel<<<nblkA, 1024, 0, stream>>>(offs, bsum, n3);
  scatter_kernel<<<(El + 255) / 256, 256, 0, stream>>>(ei_l, El, offs, 0, perm_l);
  scatter_kernel<<<(Em + 255) / 256, 256, 0, stream>>>(ei_m, Em, offs + NN, El, perm_m);
  scatter_kernel<<<(Eg + 255) / 256, 256, 0, stream>>>(ei_g, Eg, offs + 2 * NN, El + Em, perm_g);

  // Edge message passes (dst-sorted order, in-tile segment reduction)
  edge_kernel<<<(El + 63) / 64, 256, 0, stream>>>(x, ei_l, ea_l, perm_l, Wa1, ba1, ba2,
                                                  W1a_a, W1b_a, W2_a, la, El);
  edge_kernel<<<(Em + 63) / 64, 256, 0, stream>>>(x, ei_m, ea_m, perm_m, Wb1, bb1, bb2,
                                                  W1a_b, W1b_b, W2_b, ma, Em);
  edge_kernel<<<(Eg + 63) / 64, 256, 0, stream>>>(x, ei_g, ea_g, perm_g, Wc1, bc1, bc2,
                                                  W1a_c, W1b_c, W2_c, lo, Eg);

  // Node update + LayerNorm
  node_kernel<<<(NN + 63) / 64, 256, 0, stream>>>(x, la, ma, lo, Wg_s, Wu1_s, Wu2_s,
                                                  bg, bu1, bu2, gamma, beta, (float*)d_out);
}

// Round 4
// 554.593 us; speedup vs baseline: 3.1503x; 1.0755x over previous
//
#include <hip/hip_runtime.h>

typedef __attribute__((ext_vector_type(8))) short bf16x8;
typedef __attribute__((ext_vector_type(8))) unsigned short ushort8;
typedef __attribute__((ext_vector_type(4))) float f32x4;

#define NN 50000
#define HH 128

static __device__ __forceinline__ unsigned short f2bf(float f) {
  unsigned u = __builtin_bit_cast(unsigned, f);
  u = u + 0x7FFFu + ((u >> 16) & 1u);
  return (unsigned short)(u >> 16);
}

static __device__ __forceinline__ bf16x8 bfrag(const unsigned short* __restrict__ w,
                                               int kt, int nt, int lane) {
  return *reinterpret_cast<const bf16x8*>(w + (((kt * 8 + nt) * 64 + lane) << 3));
}

// x (fp32) -> xb (bf16), 8 elems/thread
__global__ void cvt_x_kernel(const float* __restrict__ x, unsigned short* __restrict__ xb,
                             int total8) {
  int i = blockIdx.x * 256 + threadIdx.x;
  if (i >= total8) return;
  const float4* p = reinterpret_cast<const float4*>(x + (long)i * 8);
  float4 f0 = p[0], f1 = p[1];
  ushort8 u;
  u[0] = f2bf(f0.x); u[1] = f2bf(f0.y); u[2] = f2bf(f0.z); u[3] = f2bf(f0.w);
  u[4] = f2bf(f1.x); u[5] = f2bf(f1.y); u[6] = f2bf(f1.z); u[7] = f2bf(f1.w);
  *reinterpret_cast<ushort8*>(xb + (long)i * 8) = u;
}

// Fused weight swizzle: 10 jobs with K=128 (64 blocks each), 2 jobs with K=512 (256 blocks).
// out[((kt*8+nt)*64+lane)*8+j] = bf16(W[kt*32+(lane>>4)*8+j][nt*16+(lane&15)])
struct SwzJobs {
  const float* src[12];
  unsigned short* dst[12];
};
__global__ void swz_all_kernel(SwzJobs jobs) {
  int b = blockIdx.x;
  int job, blk;
  if (b < 640) { job = b >> 6; blk = b & 63; }
  else { b -= 640; job = 10 + (b >> 8); blk = b & 255; }
  int o = blk * 256 + threadIdx.x;
  int j = o & 7, lane = (o >> 3) & 63, nt = (o >> 9) & 7, kt = o >> 12;
  int row = kt * 32 + (lane >> 4) * 8 + j;
  int col = nt * 16 + (lane & 15);
  jobs.dst[job][o] = f2bf(jobs.src[job][row * 128 + col]);
}

// ---- counting-sort by destination (two-level parallel scan) ----
__global__ void hist3_kernel(const int* __restrict__ eiL, const int* __restrict__ eiM,
                             const int* __restrict__ eiG, int El, int Em, int Eg,
                             int* __restrict__ cnt) {
  int e = blockIdx.x * 256 + threadIdx.x;
  const int* ei; int E, off;
  if (e < El) { ei = eiL; E = El; off = 0; }
  else if (e < El + Em) { e -= El; ei = eiM; E = Em; off = NN; }
  else { e -= El + Em; if (e >= Eg) return; ei = eiG; E = Eg; off = 2 * NN; }
  atomicAdd(cnt + off + ei[E + e], 1);
}

// per-block exclusive scan of 1024-chunks + block sums
__global__ void scanA_kernel(const int* __restrict__ cnt, int* __restrict__ offs,
                             int* __restrict__ bsum, int n) {
  const int t = threadIdx.x, lane = t & 63, w = t >> 6;
  const int i = blockIdx.x * 1024 + t;
  __shared__ int wsum[16], wpre[16];
  int v = (i < n) ? cnt[i] : 0;
  int inc = v;
#pragma unroll
  for (int d = 1; d < 64; d <<= 1) {
    int o = __shfl_up(inc, d, 64);
    if (lane >= d) inc += o;
  }
  if (lane == 63) wsum[w] = inc;
  __syncthreads();
  if (t == 0) {
    int run = 0;
#pragma unroll
    for (int k = 0; k < 16; ++k) { wpre[k] = run; run += wsum[k]; }
    wsum[0] = run;
  }
  __syncthreads();
  if (i < n) offs[i] = wpre[w] + inc - v;
  if (t == 0) bsum[blockIdx.x] = wsum[0];
}

// exclusive scan of block sums (n <= 256), in place
__global__ void scanB_kernel(int* __restrict__ bsum, int n) {
  const int t = threadIdx.x, lane = t & 63, w = t >> 6;
  __shared__ int wsum[4];
  int v = (t < n) ? bsum[t] : 0;
  int inc = v;
#pragma unroll
  for (int d = 1; d < 64; d <<= 1) {
    int o = __shfl_up(inc, d, 64);
    if (lane >= d) inc += o;
  }
  if (lane == 63) wsum[w] = inc;
  __syncthreads();
  int wo = 0;
  for (int k = 0; k < w; ++k) wo += wsum[k];
  if (t < n) bsum[t] = wo + inc - v;
}

__global__ void scanC_kernel(int* __restrict__ offs, const int* __restrict__ bsum, int n) {
  int i = blockIdx.x * 1024 + threadIdx.x;
  if (i < n) offs[i] += bsum[blockIdx.x];
}

// offs consumed (post-increment). perm_all gets ORIGINAL (per-scale) edge ids, globally
// ordered as [sorted-local | sorted-medium | sorted-long].
__global__ void scatter3_kernel(const int* __restrict__ eiL, const int* __restrict__ eiM,
                                const int* __restrict__ eiG, int El, int Em, int Eg,
                                int* __restrict__ offs, int* __restrict__ perm_all) {
  int e = blockIdx.x * 256 + threadIdx.x;
  const int* ei; int E, off;
  if (e < El) { ei = eiL; E = El; off = 0; }
  else if (e < El + Em) { e -= El; ei = eiM; E = Em; off = NN; }
  else { e -= El + Em; if (e >= Eg) return; ei = eiG; E = Eg; off = 2 * NN; }
  int p = atomicAdd(offs + off + ei[E + e], 1);
  perm_all[p] = e;
}

// Per-scale edge message MLP + segment-reduced scatter-add (edges dst-sorted via perm).
// msg = relu([x[src],x[dst],ea] @ W1 + b1) @ W2 + b2 ; agg[dst] += msg
__global__ __launch_bounds__(256) void edge_kernel(
    const unsigned short* __restrict__ xb, const int* __restrict__ ei,
    const float* __restrict__ ea, const int* __restrict__ perm,
    const float* __restrict__ W1f, const float* __restrict__ b1, const float* __restrict__ b2,
    const unsigned short* __restrict__ W1a, const unsigned short* __restrict__ W1b,
    const unsigned short* __restrict__ W2, float* __restrict__ agg, int E) {
  // union: As[64][136] bf16 | Ad[64][136] bf16 (34816 B) --later--> msgf[64][128] f32 (32768 B)
  __shared__ char smem[64 * 136 * 2 * 2];
  unsigned short (*As)[136] = (unsigned short(*)[136])smem;
  unsigned short (*Ad)[136] = (unsigned short(*)[136])(smem + 64 * 136 * 2);
  float* msgf = (float*)smem;
  __shared__ float eas[64][4];
  __shared__ int dsts[64];
  __shared__ int srcs[64];
  __shared__ int heads[64];
  __shared__ int nheads_s;
  const int t = threadIdx.x;

  // XCD-chunked bijective swizzle (m204): consecutive sorted tiles -> same XCD.
  const int nwg = gridDim.x, bid = blockIdx.x;
  const int q = nwg >> 3, r = nwg & 7;
  const int xcd = bid & 7, idx = bid >> 3;
  const int swz = (xcd < r ? xcd * (q + 1) : r * (q + 1) + (xcd - r) * q) + idx;
  const int e0 = swz * 64;

  if (t < 64) {
    int ge = e0 + t;
    int oe = (ge < E) ? perm[ge] : -1;
    int s = -1, d = -1;
    float a0 = 0.f, a1 = 0.f, a2 = 0.f;
    if (oe >= 0) {
      s = ei[oe];
      d = ei[E + oe];
      a0 = ea[(long)oe * 3 + 0];
      a1 = ea[(long)oe * 3 + 1];
      a2 = ea[(long)oe * 3 + 2];
    }
    srcs[t] = s; dsts[t] = d;
    eas[t][0] = a0; eas[t][1] = a1; eas[t][2] = a2;
    // segment heads over sorted dsts (wave 0 only)
    bool ishead = (d >= 0) && (t == 0 || dsts[t - 1] != d);
    unsigned long long mask = __ballot(ishead);
    if (ishead) {
      int rank = __popcll(mask & ((1ull << t) - 1ull));
      heads[rank] = t;
    }
    if (t == 0) nheads_s = __popcll(mask);
  }
  __syncthreads();

  // Stage: gather bf16 rows, 16B per lane-load, no conversion math
  for (int idx2 = t; idx2 < 64 * 16; idx2 += 256) {
    int e = idx2 >> 4, c8 = (idx2 & 15) << 3;
    int s = srcs[e], d = dsts[e];
    ushort8 vs = (ushort8){0, 0, 0, 0, 0, 0, 0, 0};
    ushort8 vd = vs;
    if (s >= 0) {
      vs = *reinterpret_cast<const ushort8*>(xb + (long)s * HH + c8);
      vd = *reinterpret_cast<const ushort8*>(xb + (long)d * HH + c8);
    }
    *reinterpret_cast<ushort8*>(&As[e][c8]) = vs;
    *reinterpret_cast<ushort8*>(&Ad[e][c8]) = vd;
  }
  __syncthreads();

  const int wave = t >> 6, lane = t & 63;
  const int lr = lane & 15, lgp = lane >> 4;

  // GEMM1: h = x_src @ W1a + x_dst @ W1b   (each wave owns 16 edge rows)
  f32x4 acc[8];
#pragma unroll
  for (int nt = 0; nt < 8; ++nt) acc[nt] = (f32x4){0.f, 0.f, 0.f, 0.f};
#pragma unroll
  for (int kt = 0; kt < 4; ++kt) {
    bf16x8 a_s = *reinterpret_cast<const bf16x8*>(&As[wave * 16 + lr][kt * 32 + lgp * 8]);
    bf16x8 a_d = *reinterpret_cast<const bf16x8*>(&Ad[wave * 16 + lr][kt * 32 + lgp * 8]);
#pragma unroll
    for (int nt = 0; nt < 8; ++nt) {
      acc[nt] = __builtin_amdgcn_mfma_f32_16x16x32_bf16(a_s, bfrag(W1a, kt, nt, lane), acc[nt], 0, 0, 0);
      acc[nt] = __builtin_amdgcn_mfma_f32_16x16x32_bf16(a_d, bfrag(W1b, kt, nt, lane), acc[nt], 0, 0, 0);
    }
  }

  // Epilogue 1: + b1 + ea rank-3 (fp32), relu, h1 -> LDS (wave-private rows, no barrier)
#pragma unroll
  for (int nt = 0; nt < 8; ++nt) {
    int col = nt * 16 + lr;
    float wc0 = W1f[256 * HH + col];
    float wc1 = W1f[257 * HH + col];
    float wc2 = W1f[258 * HH + col];
    float bb = b1[col];
#pragma unroll
    for (int r = 0; r < 4; ++r) {
      int row = wave * 16 + lgp * 4 + r;
      float v = acc[nt][r] + bb + eas[row][0] * wc0 + eas[row][1] * wc1 + eas[row][2] * wc2;
      As[row][col] = f2bf(fmaxf(v, 0.f));
    }
  }

  // GEMM2: msg = h1 @ W2 (reads own wave's As rows only)
  f32x4 acc2[8];
#pragma unroll
  for (int nt = 0; nt < 8; ++nt) acc2[nt] = (f32x4){0.f, 0.f, 0.f, 0.f};
#pragma unroll
  for (int kt = 0; kt < 4; ++kt) {
    bf16x8 a = *reinterpret_cast<const bf16x8*>(&As[wave * 16 + lr][kt * 32 + lgp * 8]);
#pragma unroll
    for (int nt = 0; nt < 8; ++nt) {
      acc2[nt] = __builtin_amdgcn_mfma_f32_16x16x32_bf16(a, bfrag(W2, kt, nt, lane), acc2[nt], 0, 0, 0);
    }
  }

  __syncthreads();  // everyone done reading As/Ad -> safe to overlay msgf

  // msg rows (+b2) -> LDS fp32; invalid rows -> 0
#pragma unroll
  for (int nt = 0; nt < 8; ++nt) {
    int col = nt * 16 + lr;
    float bb = b2[col];
#pragma unroll
    for (int r = 0; r < 4; ++r) {
      int row = wave * 16 + lgp * 4 + r;
      msgf[row * 128 + col] = (dsts[row] >= 0) ? acc2[nt][r] + bb : 0.f;
    }
  }
  __syncthreads();

  // Segment reduce in LDS, one atomicAdd per (unique dst, col)
  const int nh = nheads_s;
  const int col = t & 127;
  for (int hi = t >> 7; hi < nh; hi += 2) {
    int h = heads[hi];
    int en = (hi + 1 < nh) ? heads[hi + 1] : 64;
    float s = 0.f;
    for (int rr = h; rr < en; ++rr) s += msgf[rr * 128 + col];
    atomicAdd(agg + (long)dsts[h] * HH + col, s);
  }
}

// Node update: u=[x,la,ma,lo]; gate=sigmoid(u@Wg+bg); upd=relu(u@Wu1+bu1)@Wu2+bu2;
// out = LN(gate*upd + (1-gate)*x) * gamma + beta
__global__ __launch_bounds__(256) void node_kernel(
    const float* __restrict__ x, const unsigned short* __restrict__ xb,
    const float* __restrict__ la, const float* __restrict__ ma, const float* __restrict__ lo,
    const unsigned short* __restrict__ Wg, const unsigned short* __restrict__ Wu1,
    const unsigned short* __restrict__ Wu2,
    const float* __restrict__ bg, const float* __restrict__ bu1, const float* __restrict__ bu2,
    const float* __restrict__ gamma, const float* __restrict__ beta,
    float* __restrict__ out) {
  __shared__ unsigned short Hs[64][136];
  const int t = threadIdx.x;
  const int n0 = blockIdx.x * 64;
  const int wave = t >> 6, lane = t & 63;
  const int lr = lane & 15, lgp = lane >> 4;

  f32x4 accG[8], accH[8];
#pragma unroll
  for (int nt = 0; nt < 8; ++nt) {
    accG[nt] = (f32x4){0.f, 0.f, 0.f, 0.f};
    accH[nt] = (f32x4){0.f, 0.f, 0.f, 0.f};
  }
  const int arow = n0 + wave * 16 + lr;
  const bool aok = arow < NN;

#pragma unroll
  for (int kt = 0; kt < 16; ++kt) {
    int cb = ((kt & 3) << 5) + (lgp << 3);
    bf16x8 a = (bf16x8){0, 0, 0, 0, 0, 0, 0, 0};
    if (kt < 4) {
      if (aok) a = *reinterpret_cast<const bf16x8*>(xb + (long)arow * HH + cb);
    } else {
      const float* S = (kt < 8) ? la : (kt < 12) ? ma : lo;
      if (aok) {
        float4 f0 = *reinterpret_cast<const float4*>(S + (long)arow * HH + cb);
        float4 f1 = *reinterpret_cast<const float4*>(S + (long)arow * HH + cb + 4);
        a[0] = (short)f2bf(f0.x); a[1] = (short)f2bf(f0.y);
        a[2] = (short)f2bf(f0.z); a[3] = (short)f2bf(f0.w);
        a[4] = (short)f2bf(f1.x); a[5] = (short)f2bf(f1.y);
        a[6] = (short)f2bf(f1.z); a[7] = (short)f2bf(f1.w);
      }
    }
#pragma unroll
    for (int nt = 0; nt < 8; ++nt) {
      accG[nt] = __builtin_amdgcn_mfma_f32_16x16x32_bf16(a, bfrag(Wg, kt, nt, lane), accG[nt], 0, 0, 0);
      accH[nt] = __builtin_amdgcn_mfma_f32_16x16x32_bf16(a, bfrag(Wu1, kt, nt, lane), accH[nt], 0, 0, 0);
    }
  }

#pragma unroll
  for (int nt = 0; nt < 8; ++nt) {
    int col = nt * 16 + lr;
    float bgv = bg[col], bhv = bu1[col];
#pragma unroll
    for (int r = 0; r < 4; ++r) {
      float g = 1.f / (1.f + __expf(-(accG[nt][r] + bgv)));
      accG[nt][r] = g;
      float h = fmaxf(accH[nt][r] + bhv, 0.f);
      Hs[wave * 16 + lgp * 4 + r][col] = f2bf(h);
    }
  }

  f32x4 accU[8];
#pragma unroll
  for (int nt = 0; nt < 8; ++nt) accU[nt] = (f32x4){0.f, 0.f, 0.f, 0.f};
#pragma unroll
  for (int kt = 0; kt < 4; ++kt) {
    bf16x8 a = *reinterpret_cast<const bf16x8*>(&Hs[wave * 16 + lr][kt * 32 + lgp * 8]);
#pragma unroll
    for (int nt = 0; nt < 8; ++nt) {
      accU[nt] = __builtin_amdgcn_mfma_f32_16x16x32_bf16(a, bfrag(Wu2, kt, nt, lane), accU[nt], 0, 0, 0);
    }
  }

#pragma unroll
  for (int nt = 0; nt < 8; ++nt) {
    int col = nt * 16 + lr;
    float b2v = bu2[col];
#pragma unroll
    for (int r = 0; r < 4; ++r) {
      int row = n0 + wave * 16 + lgp * 4 + r;
      float xv = (row < NN) ? x[(long)row * HH + col] : 0.f;
      float u = accU[nt][r] + b2v;
      float g = accG[nt][r];
      accU[nt][r] = g * u + (1.f - g) * xv;
    }
  }

#pragma unroll
  for (int r = 0; r < 4; ++r) {
    int row = n0 + wave * 16 + lgp * 4 + r;
    float s = 0.f;
#pragma unroll
    for (int nt = 0; nt < 8; ++nt) s += accU[nt][r];
    s += __shfl_xor(s, 1, 64);
    s += __shfl_xor(s, 2, 64);
    s += __shfl_xor(s, 4, 64);
    s += __shfl_xor(s, 8, 64);
    float mu = s * (1.f / 128.f);
    float q = 0.f;
#pragma unroll
    for (int nt = 0; nt < 8; ++nt) {
      float d = accU[nt][r] - mu;
      q += d * d;
    }
    q += __shfl_xor(q, 1, 64);
    q += __shfl_xor(q, 2, 64);
    q += __shfl_xor(q, 4, 64);
    q += __shfl_xor(q, 8, 64);
    float rs = rsqrtf(q * (1.f / 128.f) + 1e-5f);
    if (row < NN) {
#pragma unroll
      for (int nt = 0; nt < 8; ++nt) {
        int col = nt * 16 + lr;
        out[(long)row * HH + col] = (accU[nt][r] - mu) * rs * gamma[col] + beta[col];
      }
    }
  }
}

extern "C" void kernel_launch(void* const* d_in, const int* in_sizes, int n_in,
                              void* d_out, int out_size, void* d_ws, size_t ws_size,
                              hipStream_t stream) {
  const float* x = (const float*)d_in[0];
  const int* ei_l = (const int*)d_in[1];
  const float* ea_l = (const float*)d_in[2];
  const int* ei_m = (const int*)d_in[3];
  const float* ea_m = (const float*)d_in[4];
  const int* ei_g = (const int*)d_in[5];
  const float* ea_g = (const float*)d_in[6];
  const float* Wa1 = (const float*)d_in[7];
  const float* ba1 = (const float*)d_in[8];
  const float* Wa2 = (const float*)d_in[9];
  const float* ba2 = (const float*)d_in[10];
  const float* Wb1 = (const float*)d_in[11];
  const float* bb1 = (const float*)d_in[12];
  const float* Wb2 = (const float*)d_in[13];
  const float* bb2 = (const float*)d_in[14];
  const float* Wc1 = (const float*)d_in[15];
  const float* bc1 = (const float*)d_in[16];
  const float* Wc2 = (const float*)d_in[17];
  const float* bc2 = (const float*)d_in[18];
  const float* Wg = (const float*)d_in[19];
  const float* bg = (const float*)d_in[20];
  const float* Wu1 = (const float*)d_in[21];
  const float* bu1 = (const float*)d_in[22];
  const float* Wu2 = (const float*)d_in[23];
  const float* bu2 = (const float*)d_in[24];
  const float* gamma = (const float*)d_in[25];
  const float* beta = (const float*)d_in[26];

  const int El = in_sizes[1] / 2;
  const int Em = in_sizes[3] / 2;
  const int Eg = in_sizes[5] / 2;

  // Workspace layout
  float* la = (float*)d_ws;                 // N*H
  float* ma = la + (size_t)NN * HH;         // N*H
  float* lo = ma + (size_t)NN * HH;         // N*H
  unsigned short* xb = (unsigned short*)(lo + (size_t)NN * HH);  // N*H bf16
  unsigned short* wp = xb + (size_t)NN * HH;
  unsigned short* W1a_a = wp; wp += 128 * 128;
  unsigned short* W1b_a = wp; wp += 128 * 128;
  unsigned short* W2_a  = wp; wp += 128 * 128;
  unsigned short* W1a_b = wp; wp += 128 * 128;
  unsigned short* W1b_b = wp; wp += 128 * 128;
  unsigned short* W2_b  = wp; wp += 128 * 128;
  unsigned short* W1a_c = wp; wp += 128 * 128;
  unsigned short* W1b_c = wp; wp += 128 * 128;
  unsigned short* W2_c  = wp; wp += 128 * 128;
  unsigned short* Wu2_s = wp; wp += 128 * 128;
  unsigned short* Wg_s  = wp; wp += 512 * 128;
  unsigned short* Wu1_s = wp; wp += 512 * 128;
  int* ip = (int*)wp;
  int* perm_all = ip; ip += El + Em + Eg;   // [sorted-l | sorted-m | sorted-g]
  int* perm_l = perm_all;
  int* perm_m = perm_all + El;
  int* perm_g = perm_all + El + Em;
  int* cnt  = ip; ip += 3 * NN;   // concatenated histograms [l|m|g]
  int* offs = ip; ip += 3 * NN;
  int* bsum = ip; ip += 256;

  // Zero aggregation buffers + histograms
  hipMemsetAsync(d_ws, 0, (size_t)3 * NN * HH * sizeof(float), stream);
  hipMemsetAsync(cnt, 0, 3 * NN * sizeof(int), stream);

  // x -> bf16
  cvt_x_kernel<<<(NN * HH / 8 + 255) / 256, 256, 0, stream>>>(x, xb, NN * HH / 8);

  // Fused weight swizzle: 10×K=128 jobs then 2×K=512 jobs
  SwzJobs jobs;
  jobs.src[0] = Wa1;            jobs.dst[0] = W1a_a;
  jobs.src[1] = Wa1 + 128*128;  jobs.dst[1] = W1b_a;
  jobs.src[2] = Wa2;            jobs.dst[2] = W2_a;
  jobs.src[3] = Wb1;            jobs.dst[3] = W1a_b;
  jobs.src[4] = Wb1 + 128*128;  jobs.dst[4] = W1b_b;
  jobs.src[5] = Wb2;            jobs.dst[5] = W2_b;
  jobs.src[6] = Wc1;            jobs.dst[6] = W1a_c;
  jobs.src[7] = Wc1 + 128*128;  jobs.dst[7] = W1b_c;
  jobs.src[8] = Wc2;            jobs.dst[8] = W2_c;
  jobs.src[9] = Wu2;            jobs.dst[9] = Wu2_s;
  jobs.src[10] = Wg;            jobs.dst[10] = Wg_s;
  jobs.src[11] = Wu1;           jobs.dst[11] = Wu1_s;
  swz_all_kernel<<<640 + 512, 256, 0, stream>>>(jobs);

  // Counting sort by dst: fused hist -> two-level scan -> fused scatter
  const int Etot = El + Em + Eg;
  hist3_kernel<<<(Etot + 255) / 256, 256, 0, stream>>>(ei_l, ei_m, ei_g, El, Em, Eg, cnt);
  const int n3 = 3 * NN;
  const int nblkA = (n3 + 1023) / 1024;
  scanA_kernel<<<nblkA, 1024, 0, stream>>>(cnt, offs, bsum, n3);
  scanB_kernel<<<1, 256, 0, stream>>>(bsum, nblkA);
  scanC_kernel<<<nblkA, 1024, 0, stream>>>(offs, bsum, n3);
  scatter3_kernel<<<(Etot + 255) / 256, 256, 0, stream>>>(ei_l, ei_m, ei_g, El, Em, Eg,
                                                          offs, perm_all);

  // Edge message passes (dst-sorted order, in-tile segment reduction)
  edge_kernel<<<(El + 63) / 64, 256, 0, stream>>>(xb, ei_l, ea_l, perm_l, Wa1, ba1, ba2,
                                                  W1a_a, W1b_a, W2_a, la, El);
  edge_kernel<<<(Em + 63) / 64, 256, 0, stream>>>(xb, ei_m, ea_m, perm_m, Wb1, bb1, bb2,
                                                  W1a_b, W1b_b, W2_b, ma, Em);
  edge_kernel<<<(Eg + 63) / 64, 256, 0, stream>>>(xb, ei_g, ea_g, perm_g, Wc1, bc1, bc2,
                                                  W1a_c, W1b_c, W2_c, lo, Eg);

  // Node update + LayerNorm
  node_kernel<<<(NN + 63) / 64, 256, 0, stream>>>(x, xb, la, ma, lo, Wg_s, Wu1_s, Wu2_s,
                                                  bg, bu1, bu2, gamma, beta, (float*)d_out);
}

// Round 5
// 485.780 us; speedup vs baseline: 3.5966x; 1.1417x over previous
//
#include <hip/hip_runtime.h>

typedef __attribute__((ext_vector_type(8))) short bf16x8;
typedef __attribute__((ext_vector_type(8))) unsigned short ushort8;
typedef __attribute__((ext_vector_type(4))) float f32x4;

#define NN 50000
#define HH 128

static __device__ __forceinline__ unsigned short f2bf(float f) {
  unsigned u = __builtin_bit_cast(unsigned, f);
  u = u + 0x7FFFu + ((u >> 16) & 1u);
  return (unsigned short)(u >> 16);
}

static __device__ __forceinline__ float bf2f(unsigned short b) {
  return __builtin_bit_cast(float, ((unsigned)b) << 16);
}

static __device__ __forceinline__ bf16x8 bfrag(const unsigned short* __restrict__ w,
                                               int kt, int nt, int lane) {
  return *reinterpret_cast<const bf16x8*>(w + (((kt * 8 + nt) * 64 + lane) << 3));
}

// Fused weight swizzle: 10 jobs with K=128 (64 blocks each), 2 jobs with K=512 (256 blocks).
// out[((kt*8+nt)*64+lane)*8+j] = bf16(W[kt*32+(lane>>4)*8+j][nt*16+(lane&15)])
struct SwzJobs {
  const float* src[12];
  unsigned short* dst[12];
};
__global__ void swz_all_kernel(SwzJobs jobs) {
  int b = blockIdx.x;
  int job, blk;
  if (b < 640) { job = b >> 6; blk = b & 63; }
  else { b -= 640; job = 10 + (b >> 8); blk = b & 255; }
  int o = blk * 256 + threadIdx.x;
  int j = o & 7, lane = (o >> 3) & 63, nt = (o >> 9) & 7, kt = o >> 12;
  int row = kt * 32 + (lane >> 4) * 8 + j;
  int col = nt * 16 + (lane & 15);
  jobs.dst[job][o] = f2bf(jobs.src[job][row * 128 + col]);
}

// P/Q precompute: 6 GEMMs out = x @ W (+bias), bf16 row-major output.
struct PQJobs {
  const unsigned short* Wswz[6];
  const float* bias[6];     // nullptr for P jobs
  unsigned short* out[6];
};
__global__ __launch_bounds__(256) void pq_kernel(const float* __restrict__ x, PQJobs jobs) {
  __shared__ unsigned short As[64][136];
  const int t = threadIdx.x;
  const int n0 = blockIdx.x * 64;
  for (int idx = t; idx < 64 * 32; idx += 256) {
    int e = idx >> 5, c4 = (idx & 31) << 2;
    int row = n0 + e;
    float4 v = make_float4(0.f, 0.f, 0.f, 0.f);
    if (row < NN) v = *reinterpret_cast<const float4*>(x + (long)row * HH + c4);
    *reinterpret_cast<ushort4*>(&As[e][c4]) =
        make_ushort4(f2bf(v.x), f2bf(v.y), f2bf(v.z), f2bf(v.w));
  }
  __syncthreads();
  const int wave = t >> 6, lane = t & 63;
  const int lr = lane & 15, lgp = lane >> 4;
  bf16x8 afr[4];
#pragma unroll
  for (int kt = 0; kt < 4; ++kt)
    afr[kt] = *reinterpret_cast<const bf16x8*>(&As[wave * 16 + lr][kt * 32 + lgp * 8]);
#pragma unroll
  for (int jb = 0; jb < 6; ++jb) {
    f32x4 acc[8];
#pragma unroll
    for (int nt = 0; nt < 8; ++nt) acc[nt] = (f32x4){0.f, 0.f, 0.f, 0.f};
#pragma unroll
    for (int kt = 0; kt < 4; ++kt)
#pragma unroll
      for (int nt = 0; nt < 8; ++nt)
        acc[nt] = __builtin_amdgcn_mfma_f32_16x16x32_bf16(
            afr[kt], bfrag(jobs.Wswz[jb], kt, nt, lane), acc[nt], 0, 0, 0);
    const float* bi = jobs.bias[jb];
    unsigned short* O = jobs.out[jb];
#pragma unroll
    for (int nt = 0; nt < 8; ++nt) {
      int col = nt * 16 + lr;
      float bv = bi ? bi[col] : 0.f;
#pragma unroll
      for (int r = 0; r < 4; ++r) {
        int row = n0 + wave * 16 + lgp * 4 + r;
        if (row < NN) O[(long)row * HH + col] = f2bf(acc[nt][r] + bv);
      }
    }
  }
}

// ---- counting-sort by destination (two-level parallel scan) ----
__global__ void hist3_kernel(const int* __restrict__ eiL, const int* __restrict__ eiM,
                             const int* __restrict__ eiG, int El, int Em, int Eg,
                             int* __restrict__ cnt) {
  int e = blockIdx.x * 256 + threadIdx.x;
  const int* ei; int E, off;
  if (e < El) { ei = eiL; E = El; off = 0; }
  else if (e < El + Em) { e -= El; ei = eiM; E = Em; off = NN; }
  else { e -= El + Em; if (e >= Eg) return; ei = eiG; E = Eg; off = 2 * NN; }
  atomicAdd(cnt + off + ei[E + e], 1);
}

__global__ void scanA_kernel(const int* __restrict__ cnt, int* __restrict__ offs,
                             int* __restrict__ bsum, int n) {
  const int t = threadIdx.x, lane = t & 63, w = t >> 6;
  const int i = blockIdx.x * 1024 + t;
  __shared__ int wsum[16], wpre[16];
  int v = (i < n) ? cnt[i] : 0;
  int inc = v;
#pragma unroll
  for (int d = 1; d < 64; d <<= 1) {
    int o = __shfl_up(inc, d, 64);
    if (lane >= d) inc += o;
  }
  if (lane == 63) wsum[w] = inc;
  __syncthreads();
  if (t == 0) {
    int run = 0;
#pragma unroll
    for (int k = 0; k < 16; ++k) { wpre[k] = run; run += wsum[k]; }
    wsum[0] = run;
  }
  __syncthreads();
  if (i < n) offs[i] = wpre[w] + inc - v;
  if (t == 0) bsum[blockIdx.x] = wsum[0];
}

__global__ void scanB_kernel(int* __restrict__ bsum, int n) {
  const int t = threadIdx.x, lane = t & 63, w = t >> 6;
  __shared__ int wsum[4];
  int v = (t < n) ? bsum[t] : 0;
  int inc = v;
#pragma unroll
  for (int d = 1; d < 64; d <<= 1) {
    int o = __shfl_up(inc, d, 64);
    if (lane >= d) inc += o;
  }
  if (lane == 63) wsum[w] = inc;
  __syncthreads();
  int wo = 0;
  for (int k = 0; k < w; ++k) wo += wsum[k];
  if (t < n) bsum[t] = wo + inc - v;
}

__global__ void scanC_kernel(int* __restrict__ offs, const int* __restrict__ bsum, int n) {
  int i = blockIdx.x * 1024 + threadIdx.x;
  if (i < n) offs[i] += bsum[blockIdx.x];
}

__global__ void scatter3_kernel(const int* __restrict__ eiL, const int* __restrict__ eiM,
                                const int* __restrict__ eiG, int El, int Em, int Eg,
                                int* __restrict__ offs, int* __restrict__ perm_all) {
  int e = blockIdx.x * 256 + threadIdx.x;
  const int* ei; int E, off;
  if (e < El) { ei = eiL; E = El; off = 0; }
  else if (e < El + Em) { e -= El; ei = eiM; E = Em; off = NN; }
  else { e -= El + Em; if (e >= Eg) return; ei = eiG; E = Eg; off = 2 * NN; }
  int p = atomicAdd(offs + off + ei[E + e], 1);
  perm_all[p] = e;
}

// ---- merged edge kernel: all 3 scales in one launch ----
// h1 = relu(P[src] + Q[dst] + ea@W1c) built per-lane in A-fragment layout (no staging),
// msg = h1 @ W2 (+b2); segment-reduced atomic scatter into agg.
struct EScale {
  const int* ei; const float* ea; const int* perm;
  const unsigned short *P, *Q, *W2;
  const float* Wc;    // W1 + 256*128 (3x128 fp32 edge-attr rows)
  const float* b2;
  float* agg;
  int E; int tbase;
};
struct EParams { EScale s[3]; };
__global__ __launch_bounds__(256) void edge_kernel(EParams prm) {
  __shared__ float msgf[64 * 128];
  __shared__ float eas[64][4];
  __shared__ float Wc[3 * 128];
  __shared__ int dsts[64], srcs[64], heads[64];
  __shared__ int nheads_s;
  const int t = threadIdx.x;

  // XCD-chunked bijective swizzle over the global tile space.
  const int nwg = gridDim.x, bid = blockIdx.x;
  const int q = nwg >> 3, r = nwg & 7;
  const int xcd = bid & 7, idx = bid >> 3;
  const int tile = (xcd < r ? xcd * (q + 1) : r * (q + 1) + (xcd - r) * q) + idx;
  const int si = (tile >= prm.s[1].tbase) + (tile >= prm.s[2].tbase);
  const EScale S = prm.s[si];
  const int e0 = (tile - S.tbase) * 64;

  if (t < 64) {
    int ge = e0 + t;
    int oe = (ge < S.E) ? S.perm[ge] : -1;
    int s = -1, d = -1;
    float a0 = 0.f, a1 = 0.f, a2 = 0.f;
    if (oe >= 0) {
      s = S.ei[oe];
      d = S.ei[S.E + oe];
      a0 = S.ea[(long)oe * 3 + 0];
      a1 = S.ea[(long)oe * 3 + 1];
      a2 = S.ea[(long)oe * 3 + 2];
    }
    srcs[t] = s; dsts[t] = d;
    eas[t][0] = a0; eas[t][1] = a1; eas[t][2] = a2;
    bool ishead = (d >= 0) && (t == 0 || dsts[t - 1] != d);
    unsigned long long mask = __ballot(ishead);
    if (ishead) {
      int rank = __popcll(mask & ((1ull << t) - 1ull));
      heads[rank] = t;
    }
    if (t == 0) nheads_s = __popcll(mask);
  }
  for (int i = t; i < 384; i += 256) Wc[i] = S.Wc[i];
  __syncthreads();

  const int wave = t >> 6, lane = t & 63;
  const int lr = lane & 15, lgp = lane >> 4;
  const int row = wave * 16 + lr;
  const int src = srcs[row], dst = dsts[row];
  const int srow = (src >= 0) ? src : 0;
  const int drow = (dst >= 0) ? dst : 0;
  const float ea0 = eas[row][0], ea1 = eas[row][1], ea2 = eas[row][2];

  // h1 fragments in registers: relu(P[src] + Q[dst] + ea.Wc), per-lane cols kt*32+lgp*8+j
  bf16x8 af[4];
#pragma unroll
  for (int kt = 0; kt < 4; ++kt) {
    int cb = kt * 32 + lgp * 8;
    bf16x8 pf = *reinterpret_cast<const bf16x8*>(S.P + (long)srow * HH + cb);
    bf16x8 qf = *reinterpret_cast<const bf16x8*>(S.Q + (long)drow * HH + cb);
#pragma unroll
    for (int j = 0; j < 8; ++j) {
      int col = cb + j;
      float v = bf2f((unsigned short)pf[j]) + bf2f((unsigned short)qf[j]) +
                ea0 * Wc[col] + ea1 * Wc[128 + col] + ea2 * Wc[256 + col];
      af[kt][j] = (short)f2bf(fmaxf(v, 0.f));
    }
  }

  // GEMM2: msg = h1 @ W2
  f32x4 acc2[8];
#pragma unroll
  for (int nt = 0; nt < 8; ++nt) acc2[nt] = (f32x4){0.f, 0.f, 0.f, 0.f};
#pragma unroll
  for (int kt = 0; kt < 4; ++kt)
#pragma unroll
    for (int nt = 0; nt < 8; ++nt)
      acc2[nt] = __builtin_amdgcn_mfma_f32_16x16x32_bf16(
          af[kt], bfrag(S.W2, kt, nt, lane), acc2[nt], 0, 0, 0);

  // msg rows (+b2) -> LDS fp32; invalid rows -> 0
#pragma unroll
  for (int nt = 0; nt < 8; ++nt) {
    int col = nt * 16 + lr;
    float bb = S.b2[col];
#pragma unroll
    for (int r = 0; r < 4; ++r) {
      int orow = wave * 16 + lgp * 4 + r;
      msgf[orow * 128 + col] = (dsts[orow] >= 0) ? acc2[nt][r] + bb : 0.f;
    }
  }
  __syncthreads();

  // Segment reduce in LDS, one atomicAdd per (unique dst, col)
  const int nh = nheads_s;
  const int col = t & 127;
  for (int hi = t >> 7; hi < nh; hi += 2) {
    int h = heads[hi];
    int en = (hi + 1 < nh) ? heads[hi + 1] : 64;
    float s = 0.f;
    for (int rr = h; rr < en; ++rr) s += msgf[rr * 128 + col];
    atomicAdd(S.agg + (long)dsts[h] * HH + col, s);
  }
}

// Node update: u=[x,la,ma,lo]; gate=sigmoid(u@Wg+bg); upd=relu(u@Wu1+bu1)@Wu2+bu2;
// out = LN(gate*upd + (1-gate)*x) * gamma + beta
__global__ __launch_bounds__(256) void node_kernel(
    const float* __restrict__ x, const float* __restrict__ la, const float* __restrict__ ma,
    const float* __restrict__ lo,
    const unsigned short* __restrict__ Wg, const unsigned short* __restrict__ Wu1,
    const unsigned short* __restrict__ Wu2,
    const float* __restrict__ bg, const float* __restrict__ bu1, const float* __restrict__ bu2,
    const float* __restrict__ gamma, const float* __restrict__ beta,
    float* __restrict__ out) {
  __shared__ unsigned short Hs[64][136];
  const int t = threadIdx.x;
  const int n0 = blockIdx.x * 64;
  const int wave = t >> 6, lane = t & 63;
  const int lr = lane & 15, lgp = lane >> 4;

  f32x4 accG[8], accH[8];
#pragma unroll
  for (int nt = 0; nt < 8; ++nt) {
    accG[nt] = (f32x4){0.f, 0.f, 0.f, 0.f};
    accH[nt] = (f32x4){0.f, 0.f, 0.f, 0.f};
  }
  const int arow = n0 + wave * 16 + lr;
  const bool aok = arow < NN;

#pragma unroll
  for (int kt = 0; kt < 16; ++kt) {
    const float* S = (kt < 4) ? x : (kt < 8) ? la : (kt < 12) ? ma : lo;
    int cb = ((kt & 3) << 5) + (lgp << 3);
    bf16x8 a = (bf16x8){0, 0, 0, 0, 0, 0, 0, 0};
    if (aok) {
      float4 f0 = *reinterpret_cast<const float4*>(S + (long)arow * HH + cb);
      float4 f1 = *reinterpret_cast<const float4*>(S + (long)arow * HH + cb + 4);
      a[0] = (short)f2bf(f0.x); a[1] = (short)f2bf(f0.y);
      a[2] = (short)f2bf(f0.z); a[3] = (short)f2bf(f0.w);
      a[4] = (short)f2bf(f1.x); a[5] = (short)f2bf(f1.y);
      a[6] = (short)f2bf(f1.z); a[7] = (short)f2bf(f1.w);
    }
#pragma unroll
    for (int nt = 0; nt < 8; ++nt) {
      accG[nt] = __builtin_amdgcn_mfma_f32_16x16x32_bf16(a, bfrag(Wg, kt, nt, lane), accG[nt], 0, 0, 0);
      accH[nt] = __builtin_amdgcn_mfma_f32_16x16x32_bf16(a, bfrag(Wu1, kt, nt, lane), accH[nt], 0, 0, 0);
    }
  }

#pragma unroll
  for (int nt = 0; nt < 8; ++nt) {
    int col = nt * 16 + lr;
    float bgv = bg[col], bhv = bu1[col];
#pragma unroll
    for (int r = 0; r < 4; ++r) {
      float g = 1.f / (1.f + __expf(-(accG[nt][r] + bgv)));
      accG[nt][r] = g;
      float h = fmaxf(accH[nt][r] + bhv, 0.f);
      Hs[wave * 16 + lgp * 4 + r][col] = f2bf(h);
    }
  }

  f32x4 accU[8];
#pragma unroll
  for (int nt = 0; nt < 8; ++nt) accU[nt] = (f32x4){0.f, 0.f, 0.f, 0.f};
#pragma unroll
  for (int kt = 0; kt < 4; ++kt) {
    bf16x8 a = *reinterpret_cast<const bf16x8*>(&Hs[wave * 16 + lr][kt * 32 + lgp * 8]);
#pragma unroll
    for (int nt = 0; nt < 8; ++nt) {
      accU[nt] = __builtin_amdgcn_mfma_f32_16x16x32_bf16(a, bfrag(Wu2, kt, nt, lane), accU[nt], 0, 0, 0);
    }
  }

#pragma unroll
  for (int nt = 0; nt < 8; ++nt) {
    int col = nt * 16 + lr;
    float b2v = bu2[col];
#pragma unroll
    for (int r = 0; r < 4; ++r) {
      int row = n0 + wave * 16 + lgp * 4 + r;
      float xv = (row < NN) ? x[(long)row * HH + col] : 0.f;
      float u = accU[nt][r] + b2v;
      float g = accG[nt][r];
      accU[nt][r] = g * u + (1.f - g) * xv;
    }
  }

#pragma unroll
  for (int r = 0; r < 4; ++r) {
    int row = n0 + wave * 16 + lgp * 4 + r;
    float s = 0.f;
#pragma unroll
    for (int nt = 0; nt < 8; ++nt) s += accU[nt][r];
    s += __shfl_xor(s, 1, 64);
    s += __shfl_xor(s, 2, 64);
    s += __shfl_xor(s, 4, 64);
    s += __shfl_xor(s, 8, 64);
    float mu = s * (1.f / 128.f);
    float qv = 0.f;
#pragma unroll
    for (int nt = 0; nt < 8; ++nt) {
      float d = accU[nt][r] - mu;
      qv += d * d;
    }
    qv += __shfl_xor(qv, 1, 64);
    qv += __shfl_xor(qv, 2, 64);
    qv += __shfl_xor(qv, 4, 64);
    qv += __shfl_xor(qv, 8, 64);
    float rs = rsqrtf(qv * (1.f / 128.f) + 1e-5f);
    if (row < NN) {
#pragma unroll
      for (int nt = 0; nt < 8; ++nt) {
        int col = nt * 16 + lr;
        out[(long)row * HH + col] = (accU[nt][r] - mu) * rs * gamma[col] + beta[col];
      }
    }
  }
}

extern "C" void kernel_launch(void* const* d_in, const int* in_sizes, int n_in,
                              void* d_out, int out_size, void* d_ws, size_t ws_size,
                              hipStream_t stream) {
  const float* x = (const float*)d_in[0];
  const int* ei_l = (const int*)d_in[1];
  const float* ea_l = (const float*)d_in[2];
  const int* ei_m = (const int*)d_in[3];
  const float* ea_m = (const float*)d_in[4];
  const int* ei_g = (const int*)d_in[5];
  const float* ea_g = (const float*)d_in[6];
  const float* Wa1 = (const float*)d_in[7];
  const float* ba1 = (const float*)d_in[8];
  const float* Wa2 = (const float*)d_in[9];
  const float* ba2 = (const float*)d_in[10];
  const float* Wb1 = (const float*)d_in[11];
  const float* bb1 = (const float*)d_in[12];
  const float* Wb2 = (const float*)d_in[13];
  const float* bb2 = (const float*)d_in[14];
  const float* Wc1 = (const float*)d_in[15];
  const float* bc1 = (const float*)d_in[16];
  const float* Wc2 = (const float*)d_in[17];
  const float* bc2 = (const float*)d_in[18];
  const float* Wg = (const float*)d_in[19];
  const float* bg = (const float*)d_in[20];
  const float* Wu1 = (const float*)d_in[21];
  const float* bu1 = (const float*)d_in[22];
  const float* Wu2 = (const float*)d_in[23];
  const float* bu2 = (const float*)d_in[24];
  const float* gamma = (const float*)d_in[25];
  const float* beta = (const float*)d_in[26];

  const int El = in_sizes[1] / 2;
  const int Em = in_sizes[3] / 2;
  const int Eg = in_sizes[5] / 2;

  // Workspace layout
  float* la = (float*)d_ws;
  float* ma = la + (size_t)NN * HH;
  float* lo = ma + (size_t)NN * HH;
  unsigned short* wp = (unsigned short*)(lo + (size_t)NN * HH);
  unsigned short* W1a_a = wp; wp += 128 * 128;
  unsigned short* W1b_a = wp; wp += 128 * 128;
  unsigned short* W2_a  = wp; wp += 128 * 128;
  unsigned short* W1a_b = wp; wp += 128 * 128;
  unsigned short* W1b_b = wp; wp += 128 * 128;
  unsigned short* W2_b  = wp; wp += 128 * 128;
  unsigned short* W1a_c = wp; wp += 128 * 128;
  unsigned short* W1b_c = wp; wp += 128 * 128;
  unsigned short* W2_c  = wp; wp += 128 * 128;
  unsigned short* Wu2_s = wp; wp += 128 * 128;
  unsigned short* Wg_s  = wp; wp += 512 * 128;
  unsigned short* Wu1_s = wp; wp += 512 * 128;
  unsigned short* P_l = wp; wp += (size_t)NN * HH;
  unsigned short* Q_l = wp; wp += (size_t)NN * HH;
  unsigned short* P_m = wp; wp += (size_t)NN * HH;
  unsigned short* Q_m = wp; wp += (size_t)NN * HH;
  unsigned short* P_g = wp; wp += (size_t)NN * HH;
  unsigned short* Q_g = wp; wp += (size_t)NN * HH;
  int* ip = (int*)wp;
  int* perm_all = ip; ip += El + Em + Eg;
  int* perm_l = perm_all;
  int* perm_m = perm_all + El;
  int* perm_g = perm_all + El + Em;
  int* cnt  = ip; ip += 3 * NN;
  int* offs = ip; ip += 3 * NN;
  int* bsum = ip; ip += 256;

  hipMemsetAsync(d_ws, 0, (size_t)3 * NN * HH * sizeof(float), stream);
  hipMemsetAsync(cnt, 0, 3 * NN * sizeof(int), stream);

  // Weight swizzles
  SwzJobs jobs;
  jobs.src[0] = Wa1;            jobs.dst[0] = W1a_a;
  jobs.src[1] = Wa1 + 128*128;  jobs.dst[1] = W1b_a;
  jobs.src[2] = Wa2;            jobs.dst[2] = W2_a;
  jobs.src[3] = Wb1;            jobs.dst[3] = W1a_b;
  jobs.src[4] = Wb1 + 128*128;  jobs.dst[4] = W1b_b;
  jobs.src[5] = Wb2;            jobs.dst[5] = W2_b;
  jobs.src[6] = Wc1;            jobs.dst[6] = W1a_c;
  jobs.src[7] = Wc1 + 128*128;  jobs.dst[7] = W1b_c;
  jobs.src[8] = Wc2;            jobs.dst[8] = W2_c;
  jobs.src[9] = Wu2;            jobs.dst[9] = Wu2_s;
  jobs.src[10] = Wg;            jobs.dst[10] = Wg_s;
  jobs.src[11] = Wu1;           jobs.dst[11] = Wu1_s;
  swz_all_kernel<<<640 + 512, 256, 0, stream>>>(jobs);

  // P/Q precompute (P = x@W1a; Q = x@W1b + b1)
  PQJobs pq;
  pq.Wswz[0] = W1a_a; pq.bias[0] = nullptr; pq.out[0] = P_l;
  pq.Wswz[1] = W1b_a; pq.bias[1] = ba1;     pq.out[1] = Q_l;
  pq.Wswz[2] = W1a_b; pq.bias[2] = nullptr; pq.out[2] = P_m;
  pq.Wswz[3] = W1b_b; pq.bias[3] = bb1;     pq.out[3] = Q_m;
  pq.Wswz[4] = W1a_c; pq.bias[4] = nullptr; pq.out[4] = P_g;
  pq.Wswz[5] = W1b_c; pq.bias[5] = bc1;     pq.out[5] = Q_g;
  pq_kernel<<<(NN + 63) / 64, 256, 0, stream>>>(x, pq);

  // Counting sort by dst
  const int Etot = El + Em + Eg;
  hist3_kernel<<<(Etot + 255) / 256, 256, 0, stream>>>(ei_l, ei_m, ei_g, El, Em, Eg, cnt);
  const int n3 = 3 * NN;
  const int nblkA = (n3 + 1023) / 1024;
  scanA_kernel<<<nblkA, 1024, 0, stream>>>(cnt, offs, bsum, n3);
  scanB_kernel<<<1, 256, 0, stream>>>(bsum, nblkA);
  scanC_kernel<<<nblkA, 1024, 0, stream>>>(offs, bsum, n3);
  scatter3_kernel<<<(Etot + 255) / 256, 256, 0, stream>>>(ei_l, ei_m, ei_g, El, Em, Eg,
                                                          offs, perm_all);

  // Merged edge pass (all scales, one launch)
  const int ntl = (El + 63) / 64, ntm = (Em + 63) / 64, ntg = (Eg + 63) / 64;
  EParams ep;
  ep.s[0] = {ei_l, ea_l, perm_l, P_l, Q_l, W2_a, Wa1 + 256 * 128, ba2, la, El, 0};
  ep.s[1] = {ei_m, ea_m, perm_m, P_m, Q_m, W2_b, Wb1 + 256 * 128, bb2, ma, Em, ntl};
  ep.s[2] = {ei_g, ea_g, perm_g, P_g, Q_g, W2_c, Wc1 + 256 * 128, bc2, lo, Eg, ntl + ntm};
  edge_kernel<<<ntl + ntm + ntg, 256, 0, stream>>>(ep);

  // Node update + LayerNorm
  node_kernel<<<(NN + 63) / 64, 256, 0, stream>>>(x, la, ma, lo, Wg_s, Wu1_s, Wu2_s,
                                                  bg, bu1, bu2, gamma, beta, (float*)d_out);
}